// Round 2
// baseline (198.947 us; speedup 1.0000x reference)
//
#include <hip/hip_runtime.h>

// out[b,o] = sum_{k<4} w[o*4+k] * x[b, o*4+k] + t[b] * tw[o]
// B=1024, NUM_OUT=8192, BF=4, NUM_IN=32768. All fp32.
// Traffic: 128 MiB x-read + 32 MiB out-write (+ ~160 KiB cached w/tw)
// -> ~24.5 us floor at 6.85 TB/s (fill-kernel-demonstrated achievable BW).
//
// 4 outputs per thread: 4x float4 x-loads, 1x float4 store (16 B/lane store,
// the coalescing sweet spot), amortized index math and t/tw loads.

constexpr int BATCH   = 1024;
constexpr int NUM_OUT = 8192;
constexpr int O4      = NUM_OUT / 4;   // 2048 float4-output groups per batch row

__global__ __launch_bounds__(256) void DendriticBranchLayerSparse_62689342652745_kernel(
    const float4* __restrict__ x4,      // [B * 8192] float4 (each = one branch group)
    const float*  __restrict__ t,       // [B]
    const float4* __restrict__ w4,      // [8192] float4 (w group per output)
    const float4* __restrict__ tw4,     // [2048] float4 view of tw[8192]
    float4*       __restrict__ out4)    // [B * 2048] float4
{
    const int tid = blockIdx.x * blockDim.x + threadIdx.x;  // one per 4 outputs
    const int g   = tid & (O4 - 1);      // float4-group index within row: 0..2047
    const int b   = tid >> 11;           // batch row
    const int ob  = g << 2;              // first output index o of the 4

    // x groups for outputs ob..ob+3 of row b are x4[b*8192 + ob + j] == x4[tid*4 + j]
    const float4* xg = x4 + ((size_t)tid << 2);
    const float4 x0 = xg[0];
    const float4 x1 = xg[1];
    const float4 x2 = xg[2];
    const float4 x3 = xg[3];

    const float4 w0 = w4[ob + 0];
    const float4 w1 = w4[ob + 1];
    const float4 w2 = w4[ob + 2];
    const float4 w3 = w4[ob + 3];

    const float  tb  = t[b];        // wave-uniform -> scalar load
    const float4 twv = tw4[g];

    float4 r;
    r.x = x0.x * w0.x + x0.y * w0.y + x0.z * w0.z + x0.w * w0.w + tb * twv.x;
    r.y = x1.x * w1.x + x1.y * w1.y + x1.z * w1.z + x1.w * w1.w + tb * twv.y;
    r.z = x2.x * w2.x + x2.y * w2.y + x2.z * w2.z + x2.w * w2.w + tb * twv.z;
    r.w = x3.x * w3.x + x3.y * w3.y + x3.z * w3.z + x3.w * w3.w + tb * twv.w;

    out4[tid] = r;
}

extern "C" void kernel_launch(void* const* d_in, const int* in_sizes, int n_in,
                              void* d_out, int out_size, void* d_ws, size_t ws_size,
                              hipStream_t stream) {
    const float4* x4  = (const float4*)d_in[0];   // [1024, 32768] fp32
    const float*  t   = (const float*)d_in[1];    // [1024]
    const float4* w4  = (const float4*)d_in[2];   // [32768] fp32
    const float4* tw4 = (const float4*)d_in[3];   // [8192, 1] fp32
    float4* out4 = (float4*)d_out;                // [1024, 8192] fp32

    const int total_threads = BATCH * O4;         // 2,097,152
    const int block = 256;
    const int grid  = total_threads / block;      // 8192

    DendriticBranchLayerSparse_62689342652745_kernel<<<grid, block, 0, stream>>>(
        x4, t, w4, tw4, out4);
}